// Round 8
// baseline (348.085 us; speedup 1.0000x reference)
//
#include <hip/hip_runtime.h>
#include <hip/hip_bf16.h>

// 2-layer GCN + mean pool. N=100000, E=1600000, G=128. dims 3 -> 64 -> 128.
//   h1  = relu( (A_hat x) @ W1 + b1 )        -- aggregate 3-dim x, then tiny GEMM
//   out = (mean_g (A_hat h1)) @ W2 + b2      -- aggregate 64-dim h1, pool, tiny GEMM
// hs1 rows pre-scaled by dinv[src]; per-edge weight dinv[dst] recomputed from
// packed deg in meta.
//
// R7 -> R8: k_fill was top dispatch (100us, WRITE_SIZE 104MB for a 13.3MB
// array -- every scattered 8B write dirties a 64B line). Meta shrunk 8B -> 4B:
//   meta[p] = src | g<<17 | min(deg_dst,255)<<24
// gather2 recomputes w = rsqrtf(deg+1) (bit-identical); gather1 uses low bits.
// nmeta likewise 4B. Predict fill ~2x faster; total ~343 -> ~290us.
//
// DTYPE-ADAPTIVE: k_detect probes raw bits: flags[0]=bf16?, flags[1]=int64?

typedef __hip_bfloat16 bf16;
#define NGRAPH 128
#define NSLICE 8

__device__ __forceinline__ float b2f(bf16 v) { return __bfloat162float(v); }
__device__ __forceinline__ float bfb(unsigned short u) {
    return __uint_as_float((unsigned)u << 16);
}
__device__ __forceinline__ float fld(const void* p, long long i, int isbf) {
    return isbf ? b2f(((const bf16*)p)[i]) : ((const float*)p)[i];
}
__device__ __forceinline__ int ild(const void* p, long long i, int is64) {
    return is64 ? (int)((const long long*)p)[i] : ((const int*)p)[i];
}

// ---- dtype probe --------------------------------------------------------
__global__ void k_detect(const void* x, const void* ei, int* flags) {
    if (threadIdx.x != 0 || blockIdx.x != 0) return;
    const unsigned short* u = (const unsigned short*)x;
    int good = 0;
    for (int k = 0; k < 128; ++k) {
        int e = (u[2 * k] >> 7) & 0xFF;
        if (e >= 90 && e <= 135) ++good;
    }
    flags[0] = (good >= 96) ? 1 : 0;          // bf16 mode
    const int* w = (const int*)ei;
    int zeros = 0;
    for (int k = 0; k < 64; ++k)
        if (w[2 * k + 1] == 0) ++zeros;
    flags[1] = (zeros >= 56) ? 1 : 0;         // int64 mode
}

// ---- CSR degree ---------------------------------------------------------
__global__ void k_deg(const void* __restrict__ ei, int* __restrict__ deg, int E,
                      const int* __restrict__ flags) {
    int e = blockIdx.x * blockDim.x + threadIdx.x;
    if (e >= E) return;
    atomicAdd(&deg[ild(ei, (long long)E + e, flags[1])], 1);
}

// ---- fused node pass: boundaries + dinv + xs + nmeta --------------------
// start[g] = first node with batch >= g (batch sorted); start[NGRAPH] = n.
// nmeta[i] = g<<17 | min(deg,255)<<24   (to be OR'd with src in fill)
__global__ void k_node(const void* __restrict__ x, const void* __restrict__ batch,
                       const int* __restrict__ deg, float* __restrict__ dinv,
                       float4* __restrict__ xs, unsigned* __restrict__ nmeta,
                       int* __restrict__ start, int n, const int* __restrict__ flags) {
    int i = blockIdx.x * blockDim.x + threadIdx.x;
    if (i >= n) return;
    int is64 = flags[1], isbf = flags[0];
    int g = ild(batch, i, is64);
    int gp = (i == 0) ? -1 : ild(batch, i - 1, is64);
    for (int q = gp + 1; q <= g; ++q) start[q] = i;
    if (i == n - 1)
        for (int q = g + 1; q <= NGRAPH; ++q) start[q] = n;
    int dg = deg[i];
    float di = rsqrtf((float)(dg + 1));
    dinv[i] = di;
    nmeta[i] = ((unsigned)g << 17) | ((unsigned)min(dg, 255) << 24);
    xs[i] = make_float4(di * fld(x, 3LL * i, isbf), di * fld(x, 3LL * i + 1, isbf),
                        di * fld(x, 3LL * i + 2, isbf), 0.0f);
}

// ---- exclusive scan of (deg[i]+1) -> row_ptr (self-loop edge per node) --
__global__ void k_scanA(const int* __restrict__ deg, int* __restrict__ row_ptr,
                        int* __restrict__ bsum, int n) {
    __shared__ int s[256];
    int i = blockIdx.x * 256 + threadIdx.x;
    int v = (i < n) ? deg[i] + 1 : 0;
    s[threadIdx.x] = v;
    __syncthreads();
    for (int d = 1; d < 256; d <<= 1) {
        int t = (threadIdx.x >= d) ? s[threadIdx.x - d] : 0;
        __syncthreads();
        s[threadIdx.x] += t;
        __syncthreads();
    }
    if (i < n) row_ptr[i] = s[threadIdx.x] - v;
    if (threadIdx.x == 255) bsum[blockIdx.x] = s[255];
}

__global__ void k_scanB(int* __restrict__ bsum, int nb) {
    __shared__ int s[512];
    int v = (threadIdx.x < nb) ? bsum[threadIdx.x] : 0;
    s[threadIdx.x] = v;
    __syncthreads();
    for (int d = 1; d < 512; d <<= 1) {
        int t = (threadIdx.x >= d) ? s[threadIdx.x - d] : 0;
        __syncthreads();
        s[threadIdx.x] += t;
        __syncthreads();
    }
    if (threadIdx.x < nb) bsum[threadIdx.x] = s[threadIdx.x] - v;
}

// finalize row_ptr and seed cursor = row_ptr (fill then needs only one atomic)
__global__ void k_scanC(int* __restrict__ row_ptr, int* __restrict__ cursor,
                        const int* __restrict__ bsum, int n, int Etot) {
    int i = blockIdx.x * 256 + threadIdx.x;
    if (i < n) {
        int v = row_ptr[i] + bsum[i >> 8];
        row_ptr[i] = v;
        cursor[i] = v;
    }
    if (i == 0) row_ptr[n] = Etot;
}

// fill meta stream: edges [0,E) = real, [E,E+N) = self loops.
// meta[pos] = src | g<<17 | min(deg_dst,255)<<24
__global__ void k_fill(const void* __restrict__ ei, const unsigned* __restrict__ nmeta,
                       int* __restrict__ cursor, unsigned* __restrict__ meta, int E, int N,
                       const int* __restrict__ flags) {
    int e = blockIdx.x * blockDim.x + threadIdx.x;
    if (e >= E + N) return;
    int is64 = flags[1];
    int s, d;
    if (e < E) { s = ild(ei, e, is64); d = ild(ei, (long long)E + e, is64); }
    else       { s = d = e - E; }
    unsigned nm = nmeta[d];
    int pos = atomicAdd(&cursor[d], 1);
    meta[pos] = (unsigned)s | nm;
}

// ---- layer 1: CSR node-parallel gather (incl. self edge) ----------------
// aggx[i] = dinv[i] * sum_{p in row i} xs[meta[p] & 0x1FFFF]
__global__ void k_gather1(const float4* __restrict__ xs, const float* __restrict__ dinv,
                          const int* __restrict__ row_ptr, const unsigned* __restrict__ meta,
                          float4* __restrict__ aggx, int n) {
    int i = blockIdx.x * blockDim.x + threadIdx.x;
    if (i >= n) return;
    float ax = 0.f, ay = 0.f, az = 0.f;
    int p1 = row_ptr[i + 1];
    for (int p = row_ptr[i]; p < p1; ++p) {
        float4 v = xs[meta[p] & 0x1FFFFu];
        ax += v.x; ay += v.y; az += v.z;
    }
    float di = dinv[i];
    aggx[i] = make_float4(di * ax, di * ay, di * az, 0.0f);
}

// hs1[i][j] = dinv[i] * relu( aggx[i] . W1[:,j] + b1[j] )   (stored bf16)
__global__ void k_h1(const float4* __restrict__ aggx, const float* __restrict__ dinv,
                     const void* __restrict__ W1, const void* __restrict__ b1,
                     bf16* __restrict__ hs1, int n, const int* __restrict__ flags) {
    __shared__ float w[256];  // [0..191]=W1 (3x64 row-major), [192..255]=b1
    int isbf = flags[0];
    if (threadIdx.x < 192) w[threadIdx.x] = fld(W1, threadIdx.x, isbf);
    if (threadIdx.x < 64) w[192 + threadIdx.x] = fld(b1, threadIdx.x, isbf);
    __syncthreads();
    long long t = (long long)blockIdx.x * 256 + threadIdx.x;
    int i = (int)(t >> 6), j = (int)(t & 63);
    if (i >= n) return;
    float4 a = aggx[i];
    float di = dinv[i];
    float acc = a.x * w[j] + a.y * w[64 + j] + a.z * w[128 + j] + w[192 + j];
    hs1[(size_t)i * 64 + j] = __float2bfloat16(di * fmaxf(acc, 0.0f));
}

// ---- layer 2 + pool: edge-balanced meta stream --------------------------
// Half-wave processes alternate edges; lane = ushort2 (2 feats); unroll x4 ->
// 16 row loads in flight. g monotone within chunk -> flush-on-change.
// w = dinv[dst] recomputed as rsqrtf(deg+1) from meta bits 24..31.
__global__ void k_gather2(const ushort2* __restrict__ hs1v, const unsigned* __restrict__ meta,
                          float* __restrict__ P, int Etot, int chunk) {
    int wid = (blockIdx.x * blockDim.x + threadIdx.x) >> 6;
    int lane = threadIdx.x & 63;
    int half = lane >> 5, fl = lane & 31;
    long long base = (long long)wid * chunk;
    if (base >= Etot) return;
    long long end = base + chunk;
    if (end > Etot) end = Etot;
    float accx = 0.f, accy = 0.f;
    int gcur = -1;
    float* Pw = P + (size_t)(wid & (NSLICE - 1)) * (NGRAPH * 64);
    long long p = base + half;
#define STEP(m, h)                                                              \
    {                                                                           \
        int g = (int)((m >> 17) & 0x7Fu);                                       \
        float w = rsqrtf((float)((m >> 24) & 0xFFu) + 1.0f);                    \
        if (g != gcur) {                                                        \
            if (gcur >= 0) {                                                    \
                atomicAdd(&Pw[gcur * 64 + 2 * fl], accx);                       \
                atomicAdd(&Pw[gcur * 64 + 2 * fl + 1], accy);                   \
            }                                                                   \
            accx = accy = 0.f;                                                  \
            gcur = g;                                                           \
        }                                                                       \
        accx += w * bfb(h.x);                                                   \
        accy += w * bfb(h.y);                                                   \
    }
    for (; p + 6 < end; p += 8) {
        unsigned m0 = meta[p], m1 = meta[p + 2], m2 = meta[p + 4], m3 = meta[p + 6];
        ushort2 h0 = hs1v[(size_t)(m0 & 0x1FFFFu) * 32 + fl];
        ushort2 h1 = hs1v[(size_t)(m1 & 0x1FFFFu) * 32 + fl];
        ushort2 h2 = hs1v[(size_t)(m2 & 0x1FFFFu) * 32 + fl];
        ushort2 h3 = hs1v[(size_t)(m3 & 0x1FFFFu) * 32 + fl];
        STEP(m0, h0) STEP(m1, h1) STEP(m2, h2) STEP(m3, h3)
    }
    for (; p < end; p += 2) {
        unsigned m = meta[p];
        ushort2 h = hs1v[(size_t)(m & 0x1FFFFu) * 32 + fl];
        STEP(m, h)
    }
    if (gcur >= 0) {
        atomicAdd(&Pw[gcur * 64 + 2 * fl], accx);
        atomicAdd(&Pw[gcur * 64 + 2 * fl + 1], accy);
    }
#undef STEP
}

// out[g][j] = (sum_slices P[g]/count_g) . W2[:,j] + b2[j]  (0 if empty graph)
__global__ void k_out(const float* __restrict__ P, const int* __restrict__ start,
                      const void* __restrict__ W2, const void* __restrict__ b2v,
                      void* __restrict__ out, const int* __restrict__ flags) {
    __shared__ float pm[64];
    int g = blockIdx.x, j = threadIdx.x;
    int isbf = flags[0];
    int c = start[g + 1] - start[g];
    if (j < 64) {
        float v = 0.f;
        for (int s = 0; s < NSLICE; ++s) v += P[(size_t)s * NGRAPH * 64 + g * 64 + j];
        pm[j] = (c > 0) ? v / (float)c : 0.0f;
    }
    __syncthreads();
    float acc = 0.0f;
    if (c > 0) {
        acc = fld(b2v, j, isbf);
        for (int k = 0; k < 64; ++k) acc += pm[k] * fld(W2, k * 128 + j, isbf);
    }
    if (isbf) ((bf16*)out)[g * 128 + j] = __float2bfloat16(acc);
    else      ((float*)out)[g * 128 + j] = acc;
}

extern "C" void kernel_launch(void* const* d_in, const int* in_sizes, int n_in,
                              void* d_out, int out_size, void* d_ws, size_t ws_size,
                              hipStream_t stream) {
    const void* x    = d_in[0];
    const void* ei   = d_in[1];   // edge_index [2,E] flat: src row then dst row
    const void* batch= d_in[2];
    const void* W1   = d_in[3];
    const void* b1   = d_in[4];
    const void* W2   = d_in[5];
    const void* b2   = d_in[6];

    const int N = in_sizes[0] / 3;
    const int E = in_sizes[1] / 2;
    const int Etot = E + N;

    // ---- workspace layout (512B aligned), total ~26 MB ----
    char* ws = (char*)d_ws;
    size_t off = 0;
    auto alloc = [&](size_t bytes) {
        size_t o = off;
        off = (off + bytes + 511) & ~(size_t)511;
        return o;
    };
    int* flags      = (int*)(ws + alloc(64 * 4));
    int* deg        = (int*)(ws + alloc((size_t)N * 4));
    float* dinv     = (float*)(ws + alloc((size_t)N * 4));
    int* row_ptr    = (int*)(ws + alloc((size_t)(N + 1) * 4));
    int* cursor     = (int*)(ws + alloc((size_t)N * 4));
    int* bsum       = (int*)(ws + alloc((size_t)512 * 4));
    int* start      = (int*)(ws + alloc((size_t)(NGRAPH + 1) * 4));
    unsigned* nmeta = (unsigned*)(ws + alloc((size_t)N * 4));
    unsigned* meta  = (unsigned*)(ws + alloc((size_t)Etot * 4));
    float4* xs      = (float4*)(ws + alloc((size_t)N * 16));
    float4* aggx    = (float4*)(ws + alloc((size_t)N * 16));
    bf16* hs1       = (bf16*)(ws + alloc((size_t)N * 64 * 2));
    float* P        = (float*)(ws + alloc((size_t)NSLICE * NGRAPH * 64 * 4));
    (void)ws_size;

    (void)hipMemsetAsync(deg, 0, (size_t)N * 4, stream);
    (void)hipMemsetAsync(P, 0, (size_t)NSLICE * NGRAPH * 64 * 4, stream);

    const int nb = (N + 255) / 256;        // 391
    const int eb = (E + 255) / 256;        // 6250
    const int tb = (Etot + 255) / 256;     // 6641
    const int fb = (N * 64 + 255) / 256;   // 25000

    // gather2: 1024 blocks -> 4096 waves (~16 waves/CU), edge-balanced chunks
    const int g2blocks = 1024;
    const int g2waves = g2blocks * 4;
    const int chunk = (Etot + g2waves - 1) / g2waves;

    k_detect<<<1, 64, 0, stream>>>(x, ei, flags);
    k_deg<<<eb, 256, 0, stream>>>(ei, deg, E, flags);
    k_node<<<nb, 256, 0, stream>>>(x, batch, deg, dinv, xs, nmeta, start, N, flags);
    k_scanA<<<nb, 256, 0, stream>>>(deg, row_ptr, bsum, N);
    k_scanB<<<1, 512, 0, stream>>>(bsum, nb);
    k_scanC<<<nb, 256, 0, stream>>>(row_ptr, cursor, bsum, N, Etot);
    k_fill<<<tb, 256, 0, stream>>>(ei, nmeta, cursor, meta, E, N, flags);
    k_gather1<<<nb, 256, 0, stream>>>(xs, dinv, row_ptr, meta, aggx, N);
    k_h1<<<fb, 256, 0, stream>>>(aggx, dinv, W1, b1, hs1, N, flags);
    k_gather2<<<g2blocks, 256, 0, stream>>>((const ushort2*)hs1, meta, P, Etot, chunk);
    k_out<<<NGRAPH, 128, 0, stream>>>(P, start, W2, b2, d_out, flags);
}

// Round 9
// 266.166 us; speedup vs baseline: 1.3078x; 1.3078x over previous
//
#include <hip/hip_runtime.h>
#include <hip/hip_bf16.h>

// 2-layer GCN + mean pool. N=100000, E=1600000, G=128. dims 3 -> 64 -> 128.
//   h1  = relu( (A_hat x) @ W1 + b1 )        -- aggregate 3-dim x, then tiny GEMM
//   out = (mean_g (A_hat h1)) @ W2 + b2      -- aggregate 64-dim h1, pool, tiny GEMM
//
// R8 -> R9: k_fill's scattered 4B stores cost one 64B line each (WRITE_SIZE
// = E*64B = 109MB regardless of record size; k_deg same pathology). Replaced
// the whole scatter-CSR build (deg/scanABC/fill) with a bucketed sort:
//   k_count: LDS histogram of dst>>8 (391 buckets x 256 nodes)
//   k_bscan: bucket offset scan (+1 self slot per node), seeds cursors
//   k_split: tile multisplit (LDS stage) -> bucket-grouped edges, coalesced runs
//   k_sort : per-bucket LDS counting sort -> meta/row_ptr/dinv coalesced;
//            local hist IS deg (k_deg dies); self-records injected in place.
// meta format unchanged: src(17) | g(7)<<17 | min(deg,255)<<24.
//
// DTYPE-ADAPTIVE: k_detect probes raw bits: flags[0]=bf16?, flags[1]=int64?

typedef __hip_bfloat16 bf16;
#define NGRAPH 128
#define NSLICE 8
#define TILE_C 16384
#define TILE_S 4096
#define SCAP   12288   // k_sort LDS stage capacity (mean 4096+256, ~60 sigma safe)

__device__ __forceinline__ float b2f(bf16 v) { return __bfloat162float(v); }
__device__ __forceinline__ float bfb(unsigned short u) {
    return __uint_as_float((unsigned)u << 16);
}
__device__ __forceinline__ float fld(const void* p, long long i, int isbf) {
    return isbf ? b2f(((const bf16*)p)[i]) : ((const float*)p)[i];
}
__device__ __forceinline__ int ild(const void* p, long long i, int is64) {
    return is64 ? (int)((const long long*)p)[i] : ((const int*)p)[i];
}

// ---- dtype probe --------------------------------------------------------
__global__ void k_detect(const void* x, const void* ei, int* flags) {
    if (threadIdx.x != 0 || blockIdx.x != 0) return;
    const unsigned short* u = (const unsigned short*)x;
    int good = 0;
    for (int k = 0; k < 128; ++k) {
        int e = (u[2 * k] >> 7) & 0xFF;
        if (e >= 90 && e <= 135) ++good;
    }
    flags[0] = (good >= 96) ? 1 : 0;          // bf16 mode
    const int* w = (const int*)ei;
    int zeros = 0;
    for (int k = 0; k < 64; ++k)
        if (w[2 * k + 1] == 0) ++zeros;
    flags[1] = (zeros >= 56) ? 1 : 0;         // int64 mode
}

// ---- bucket histogram of dst>>8 ----------------------------------------
__global__ void k_count(const void* __restrict__ ei, int* __restrict__ cnt,
                        int E, int NB, const int* __restrict__ flags) {
    __shared__ int h[512];
    for (int b = threadIdx.x; b < NB; b += 256) h[b] = 0;
    __syncthreads();
    int is64 = flags[1];
    long long base = (long long)blockIdx.x * TILE_C;
    int lim = (int)min((long long)TILE_C, (long long)E - base);
    for (int k = threadIdx.x; k < lim; k += 256) {
        int d = ild(ei, (long long)E + base + k, is64);
        atomicAdd(&h[d >> 8], 1);
    }
    __syncthreads();
    for (int b = threadIdx.x; b < NB; b += 256)
        if (h[b]) atomicAdd(&cnt[b], h[b]);
}

// ---- bucket offsets: real-edge (bktoff2) and with-self (bktoff) ---------
__global__ void k_bscan(const int* __restrict__ cnt, int* __restrict__ bktoff2,
                        int* __restrict__ bktoff, int* __restrict__ gcur,
                        int N, int NB) {
    if (threadIdx.x != 0 || blockIdx.x != 0) return;
    int a = 0, b = 0;
    for (int i = 0; i < NB; ++i) {
        int nloc = min(256, N - (i << 8));
        bktoff2[i] = a; bktoff[i] = b; gcur[i] = a;
        a += cnt[i]; b += cnt[i] + nloc;
    }
    bktoff2[NB] = a; bktoff[NB] = b;
}

// ---- multisplit: bucket-grouped (dst,src) records, coalesced runs -------
__global__ void k_split(const void* __restrict__ ei, int2* __restrict__ edges2,
                        int* __restrict__ gcur, int E, int NB,
                        const int* __restrict__ flags) {
    __shared__ int hist[512], scan_[512], gbase[512], lcur[512];
    __shared__ int2 stage[TILE_S];
    int is64 = flags[1];
    long long base = (long long)blockIdx.x * TILE_S;
    int lim = (int)min((long long)TILE_S, (long long)E - base);
    for (int b = threadIdx.x; b < NB; b += 256) hist[b] = 0;
    __syncthreads();
    for (int k = threadIdx.x; k < lim; k += 256) {
        int d = ild(ei, (long long)E + base + k, is64);
        atomicAdd(&hist[d >> 8], 1);
    }
    __syncthreads();
    if (threadIdx.x == 0) {
        int a = 0;
        for (int i = 0; i < NB; ++i) { scan_[i] = a; a += hist[i]; }
    }
    __syncthreads();
    for (int b = threadIdx.x; b < NB; b += 256) {
        lcur[b] = scan_[b];
        gbase[b] = hist[b] ? atomicAdd(&gcur[b], hist[b]) : 0;
    }
    __syncthreads();
    for (int k = threadIdx.x; k < lim; k += 256) {
        int s = ild(ei, base + k, is64);
        int d = ild(ei, (long long)E + base + k, is64);
        int p = atomicAdd(&lcur[d >> 8], 1);
        stage[p] = make_int2(d, s);
    }
    __syncthreads();
    for (int t = threadIdx.x; t < lim; t += 256) {
        int2 r = stage[t];
        int b = r.x >> 8;
        edges2[gbase[b] + (t - scan_[b])] = r;
    }
}

// ---- per-bucket counting sort -> meta/row_ptr/dinv ----------------------
__global__ void k_sort(const int2* __restrict__ edges2, const void* __restrict__ batch,
                       const int* __restrict__ cnt, const int* __restrict__ bktoff2,
                       const int* __restrict__ bktoff, unsigned* __restrict__ meta,
                       int* __restrict__ row_ptr, float* __restrict__ dinv,
                       int N, int Etot, const int* __restrict__ flags) {
    __shared__ int hist[256], loff[257], lcur[256];
    __shared__ unsigned gdeg[256];
    __shared__ unsigned stage[SCAP];
    int b = blockIdx.x;
    int node0 = b << 8;
    int nloc = min(256, N - node0);
    int is64 = flags[1];
    for (int i = threadIdx.x; i < nloc; i += 256) hist[i] = 0;
    __syncthreads();
    int rbase = bktoff2[b], rcnt = cnt[b];
    for (int t = threadIdx.x; t < rcnt; t += 256) {
        int2 r = edges2[rbase + t];
        atomicAdd(&hist[r.x - node0], 1);
    }
    __syncthreads();
    if (threadIdx.x == 0) {
        int a = 0;
        for (int i = 0; i < nloc; ++i) { loff[i] = a; a += hist[i] + 1; }
        loff[nloc] = a;
    }
    __syncthreads();
    int mbase = bktoff[b];
    for (int i = threadIdx.x; i < nloc; i += 256) {
        int node = node0 + i;
        int dg = hist[i];
        dinv[node] = rsqrtf((float)(dg + 1));
        row_ptr[node] = mbase + loff[i];
        int g = ild(batch, node, is64);
        unsigned gd = ((unsigned)g << 17) | ((unsigned)min(dg, 255) << 24);
        gdeg[i] = gd;
        lcur[i] = loff[i] + 1;                 // slot 0 of each row = self record
        stage[loff[i]] = (unsigned)node | gd;
    }
    __syncthreads();
    for (int t = threadIdx.x; t < rcnt; t += 256) {
        int2 r = edges2[rbase + t];
        int dl = r.x - node0;
        int p = atomicAdd(&lcur[dl], 1);
        if (p < SCAP) stage[p] = (unsigned)r.y | gdeg[dl];
    }
    __syncthreads();
    int total = loff[nloc];
    for (int t = threadIdx.x; t < total; t += 256) meta[mbase + t] = stage[t];
    if (b == 0 && threadIdx.x == 0) row_ptr[N] = Etot;
}

// ---- node pass: graph boundaries + xs = dinv*x --------------------------
__global__ void k_node(const void* __restrict__ x, const void* __restrict__ batch,
                       const float* __restrict__ dinv, float4* __restrict__ xs,
                       int* __restrict__ start, int n, const int* __restrict__ flags) {
    int i = blockIdx.x * blockDim.x + threadIdx.x;
    if (i >= n) return;
    int is64 = flags[1], isbf = flags[0];
    int g = ild(batch, i, is64);
    int gp = (i == 0) ? -1 : ild(batch, i - 1, is64);
    for (int q = gp + 1; q <= g; ++q) start[q] = i;
    if (i == n - 1)
        for (int q = g + 1; q <= NGRAPH; ++q) start[q] = n;
    float di = dinv[i];
    xs[i] = make_float4(di * fld(x, 3LL * i, isbf), di * fld(x, 3LL * i + 1, isbf),
                        di * fld(x, 3LL * i + 2, isbf), 0.0f);
}

// ---- layer 1: CSR node-parallel gather (incl. self edge) ----------------
__global__ void k_gather1(const float4* __restrict__ xs, const float* __restrict__ dinv,
                          const int* __restrict__ row_ptr, const unsigned* __restrict__ meta,
                          float4* __restrict__ aggx, int n) {
    int i = blockIdx.x * blockDim.x + threadIdx.x;
    if (i >= n) return;
    float ax = 0.f, ay = 0.f, az = 0.f;
    int p1 = row_ptr[i + 1];
    for (int p = row_ptr[i]; p < p1; ++p) {
        float4 v = xs[meta[p] & 0x1FFFFu];
        ax += v.x; ay += v.y; az += v.z;
    }
    float di = dinv[i];
    aggx[i] = make_float4(di * ax, di * ay, di * az, 0.0f);
}

// hs1[i][j] = dinv[i] * relu( aggx[i] . W1[:,j] + b1[j] )   (stored bf16)
__global__ void k_h1(const float4* __restrict__ aggx, const float* __restrict__ dinv,
                     const void* __restrict__ W1, const void* __restrict__ b1,
                     bf16* __restrict__ hs1, int n, const int* __restrict__ flags) {
    __shared__ float w[256];  // [0..191]=W1 (3x64 row-major), [192..255]=b1
    int isbf = flags[0];
    if (threadIdx.x < 192) w[threadIdx.x] = fld(W1, threadIdx.x, isbf);
    if (threadIdx.x < 64) w[192 + threadIdx.x] = fld(b1, threadIdx.x, isbf);
    __syncthreads();
    long long t = (long long)blockIdx.x * 256 + threadIdx.x;
    int i = (int)(t >> 6), j = (int)(t & 63);
    if (i >= n) return;
    float4 a = aggx[i];
    float di = dinv[i];
    float acc = a.x * w[j] + a.y * w[64 + j] + a.z * w[128 + j] + w[192 + j];
    hs1[(size_t)i * 64 + j] = __float2bfloat16(di * fmaxf(acc, 0.0f));
}

// ---- layer 2 + pool: edge-balanced meta stream --------------------------
__global__ void k_gather2(const ushort2* __restrict__ hs1v, const unsigned* __restrict__ meta,
                          float* __restrict__ P, int Etot, int chunk) {
    int wid = (blockIdx.x * blockDim.x + threadIdx.x) >> 6;
    int lane = threadIdx.x & 63;
    int half = lane >> 5, fl = lane & 31;
    long long base = (long long)wid * chunk;
    if (base >= Etot) return;
    long long end = base + chunk;
    if (end > Etot) end = Etot;
    float accx = 0.f, accy = 0.f;
    int gcur = -1;
    float* Pw = P + (size_t)(wid & (NSLICE - 1)) * (NGRAPH * 64);
    long long p = base + half;
#define STEP(m, h)                                                              \
    {                                                                           \
        int g = (int)((m >> 17) & 0x7Fu);                                       \
        float w = rsqrtf((float)((m >> 24) & 0xFFu) + 1.0f);                    \
        if (g != gcur) {                                                        \
            if (gcur >= 0) {                                                    \
                atomicAdd(&Pw[gcur * 64 + 2 * fl], accx);                       \
                atomicAdd(&Pw[gcur * 64 + 2 * fl + 1], accy);                   \
            }                                                                   \
            accx = accy = 0.f;                                                  \
            gcur = g;                                                           \
        }                                                                       \
        accx += w * bfb(h.x);                                                   \
        accy += w * bfb(h.y);                                                   \
    }
    for (; p + 6 < end; p += 8) {
        unsigned m0 = meta[p], m1 = meta[p + 2], m2 = meta[p + 4], m3 = meta[p + 6];
        ushort2 h0 = hs1v[(size_t)(m0 & 0x1FFFFu) * 32 + fl];
        ushort2 h1 = hs1v[(size_t)(m1 & 0x1FFFFu) * 32 + fl];
        ushort2 h2 = hs1v[(size_t)(m2 & 0x1FFFFu) * 32 + fl];
        ushort2 h3 = hs1v[(size_t)(m3 & 0x1FFFFu) * 32 + fl];
        STEP(m0, h0) STEP(m1, h1) STEP(m2, h2) STEP(m3, h3)
    }
    for (; p < end; p += 2) {
        unsigned m = meta[p];
        ushort2 h = hs1v[(size_t)(m & 0x1FFFFu) * 32 + fl];
        STEP(m, h)
    }
    if (gcur >= 0) {
        atomicAdd(&Pw[gcur * 64 + 2 * fl], accx);
        atomicAdd(&Pw[gcur * 64 + 2 * fl + 1], accy);
    }
#undef STEP
}

// out[g][j] = (sum_slices P[g]/count_g) . W2[:,j] + b2[j]  (0 if empty graph)
__global__ void k_out(const float* __restrict__ P, const int* __restrict__ start,
                      const void* __restrict__ W2, const void* __restrict__ b2v,
                      void* __restrict__ out, const int* __restrict__ flags) {
    __shared__ float pm[64];
    int g = blockIdx.x, j = threadIdx.x;
    int isbf = flags[0];
    int c = start[g + 1] - start[g];
    if (j < 64) {
        float v = 0.f;
        for (int s = 0; s < NSLICE; ++s) v += P[(size_t)s * NGRAPH * 64 + g * 64 + j];
        pm[j] = (c > 0) ? v / (float)c : 0.0f;
    }
    __syncthreads();
    float acc = 0.0f;
    if (c > 0) {
        acc = fld(b2v, j, isbf);
        for (int k = 0; k < 64; ++k) acc += pm[k] * fld(W2, k * 128 + j, isbf);
    }
    if (isbf) ((bf16*)out)[g * 128 + j] = __float2bfloat16(acc);
    else      ((float*)out)[g * 128 + j] = acc;
}

extern "C" void kernel_launch(void* const* d_in, const int* in_sizes, int n_in,
                              void* d_out, int out_size, void* d_ws, size_t ws_size,
                              hipStream_t stream) {
    const void* x    = d_in[0];
    const void* ei   = d_in[1];   // edge_index [2,E] flat: src row then dst row
    const void* batch= d_in[2];
    const void* W1   = d_in[3];
    const void* b1   = d_in[4];
    const void* W2   = d_in[5];
    const void* b2   = d_in[6];

    const int N = in_sizes[0] / 3;
    const int E = in_sizes[1] / 2;
    const int Etot = E + N;
    const int NB = (N + 255) / 256;        // buckets of 256 nodes (391)

    // ---- workspace layout (512B aligned), total ~40 MB ----
    char* ws = (char*)d_ws;
    size_t off = 0;
    auto alloc = [&](size_t bytes) {
        size_t o = off;
        off = (off + bytes + 511) & ~(size_t)511;
        return o;
    };
    int* flags    = (int*)(ws + alloc(64 * 4));
    int* cnt      = (int*)(ws + alloc((size_t)NB * 4));
    int* bktoff2  = (int*)(ws + alloc((size_t)(NB + 1) * 4));
    int* bktoff   = (int*)(ws + alloc((size_t)(NB + 1) * 4));
    int* gcur     = (int*)(ws + alloc((size_t)NB * 4));
    int* start    = (int*)(ws + alloc((size_t)(NGRAPH + 1) * 4));
    int* row_ptr  = (int*)(ws + alloc((size_t)(N + 1) * 4));
    float* dinv   = (float*)(ws + alloc((size_t)N * 4));
    int2* edges2  = (int2*)(ws + alloc((size_t)E * 8));
    unsigned* meta= (unsigned*)(ws + alloc((size_t)Etot * 4));
    float4* xs    = (float4*)(ws + alloc((size_t)N * 16));
    float4* aggx  = (float4*)(ws + alloc((size_t)N * 16));
    bf16* hs1     = (bf16*)(ws + alloc((size_t)N * 64 * 2));
    float* P      = (float*)(ws + alloc((size_t)NSLICE * NGRAPH * 64 * 4));
    (void)ws_size;

    (void)hipMemsetAsync(cnt, 0, (size_t)NB * 4, stream);
    (void)hipMemsetAsync(P, 0, (size_t)NSLICE * NGRAPH * 64 * 4, stream);

    const int nb = (N + 255) / 256;                 // 391
    const int cb = (E + TILE_C - 1) / TILE_C;       // 98
    const int sb = (E + TILE_S - 1) / TILE_S;       // 391
    const int fb = (N * 64 + 255) / 256;            // 25000

    // gather2: 1024 blocks -> 4096 waves, edge-balanced chunks
    const int g2blocks = 1024;
    const int g2waves = g2blocks * 4;
    const int chunk = (Etot + g2waves - 1) / g2waves;

    k_detect<<<1, 64, 0, stream>>>(x, ei, flags);
    k_count<<<cb, 256, 0, stream>>>(ei, cnt, E, NB, flags);
    k_bscan<<<1, 64, 0, stream>>>(cnt, bktoff2, bktoff, gcur, N, NB);
    k_split<<<sb, 256, 0, stream>>>(ei, edges2, gcur, E, NB, flags);
    k_sort<<<NB, 256, 0, stream>>>(edges2, batch, cnt, bktoff2, bktoff, meta,
                                   row_ptr, dinv, N, Etot, flags);
    k_node<<<nb, 256, 0, stream>>>(x, batch, dinv, xs, start, N, flags);
    k_gather1<<<nb, 256, 0, stream>>>(xs, dinv, row_ptr, meta, aggx, N);
    k_h1<<<fb, 256, 0, stream>>>(aggx, dinv, W1, b1, hs1, N, flags);
    k_gather2<<<g2blocks, 256, 0, stream>>>((const ushort2*)hs1, meta, P, Etot, chunk);
    k_out<<<NGRAPH, 128, 0, stream>>>(P, start, W2, b2, d_out, flags);
}